// Round 9
// baseline (82.413 us; speedup 1.0000x reference)
//
#include <hip/hip_runtime.h>
#include <hip/hip_bf16.h>
#include <hip/hip_fp16.h>

#define B_   4
#define N_   1024
#define H_   16
#define HID_ 64

typedef float    f32x4  __attribute__((ext_vector_type(4)));
typedef __fp16   fp16x2 __attribute__((ext_vector_type(2)));   // cvt_pkrtz result type
typedef _Float16 f16x8  __attribute__((ext_vector_type(8)));   // MFMA operand type
typedef unsigned int u32;

union F16x8U { u32 u[4]; f16x8 v; };
union H2U    { fp16x2 f; u32 u; };

static __device__ __forceinline__ fp16x2 pkb(float x) {          // broadcast pack
    return __builtin_amdgcn_cvt_pkrtz(x, x);
}
static __device__ __forceinline__ u32 hmax0(fp16x2 a) {          // packed relu -> u32
    H2U r; fp16x2 z = { (__fp16)0.f, (__fp16)0.f };
    r.f = __builtin_elementwise_max(a, z);
    return r.u;
}
static __device__ __forceinline__ u32 pkcvt_relu(float a, float b) {
    H2U r; fp16x2 z = { (__fp16)0.f, (__fp16)0.f };
    fp16x2 s = __builtin_amdgcn_cvt_pkrtz(a, b);
    r.f = __builtin_elementwise_max(s, z);
    return r.u;
}

__global__ __launch_bounds__(256) void RelativePositionalBias_kernel(
    const float* __restrict__ pos,  // (B,N,2)
    const int*   __restrict__ mask, // (B,N) 0/1
    const float* __restrict__ W1,   // (2,64)
    const float* __restrict__ b1,   // (64)
    const float* __restrict__ W2,   // (64,64)
    const float* __restrict__ b2,   // (64)
    const float* __restrict__ W3,   // (64,16)
    const float* __restrict__ b3,   // (16)
    float* __restrict__ out)        // (B,16,N,N)
{
    const int b   = blockIdx.y;
    const int tid = threadIdx.x;
    const int w = tid >> 6;
    const int l = tid & 63;
    const int g = l >> 4;        // quarter-wave group 0..3
    const int c = l & 15;        // lane-within-group 0..15
    const int irow = blockIdx.x * 4 + w;   // this wave's output row

    // ---- W1 rows packed per lane: k = 32s + 8g + 2*e2 (+1) ----
    fp16x2 w1a[2][4], w1b[2][4], uin[2][4];
    #pragma unroll
    for (int s = 0; s < 2; ++s)
        #pragma unroll
        for (int e2 = 0; e2 < 4; ++e2) {
            int k = 32*s + 8*g + 2*e2;
            w1a[s][e2] = __builtin_amdgcn_cvt_pkrtz(W1[k],        W1[k+1]);
            w1b[s][e2] = __builtin_amdgcn_cvt_pkrtz(W1[HID_ + k], W1[HID_ + k + 1]);
        }

    // ---- Weight fragments (f16). Identity k-map for L2, permuted for L3 ----
    F16x8U W2f[2][4];   // A-frag of mfma(W2^T, h1^T): W2[32s+8g+e][16n+c]
    #pragma unroll
    for (int s = 0; s < 2; ++s)
        #pragma unroll
        for (int n = 0; n < 4; ++n)
            #pragma unroll
            for (int e = 0; e < 8; ++e)
                W2f[s][n].v[e] = (_Float16)W2[(32*s + 8*g + e) * HID_ + 16*n + c];

    F16x8U W3g[2];      // B-frag, permuted k: hid = 32s + 16*(e>>2) + 4g + (e&3)
    #pragma unroll
    for (int s = 0; s < 2; ++s)
        #pragma unroll
        for (int e = 0; e < 8; ++e)
            W3g[s].v[e] = (_Float16)W3[(32*s + 16*(e>>2) + 4*g + (e&3)) * H_ + c];

    f32x4 b2v[4];
    #pragma unroll
    for (int n = 0; n < 4; ++n)
        b2v[n] = *(const f32x4*)&b2[16*n + 4*g];
    const float b3v = b3[c];

    // ---- uin = b1 - u_i (packed f16, registers; once per wave) ----
    {
        float2 pi = *(const float2*)&pos[(b * N_ + irow) * 2];
        fp16x2 nx = pkb(-pi.x), ny = pkb(-pi.y);
        #pragma unroll
        for (int s = 0; s < 2; ++s)
            #pragma unroll
            for (int e2 = 0; e2 < 4; ++e2) {
                int k = 32*s + 8*g + 2*e2;
                fp16x2 b1p = __builtin_amdgcn_cvt_pkrtz(b1[k], b1[k+1]);
                uin[s][e2] = nx * w1a[s][e2] + (ny * w1b[s][e2] + b1p);
            }
    }

    const int mi = mask[b * N_ + irow];            // wave-uniform row mask
    const float2* pos2  = (const float2*)pos + (size_t)b * N_;
    const int*    maskj = mask + (size_t)b * N_;
    // lane (g,c) stores plane c, row irow, cols jb + 4g + q  -> j-sequential 4KB/plane
    float* const outRow = out + ((size_t)(b*H_ + c) << 20) + ((size_t)irow << 10) + 4*g;

    if (mi) {   // whole row masked: stream zeros
        const f32x4 z = { 0.f, 0.f, 0.f, 0.f };
        for (int jb = 0; jb < N_; jb += 16)
            *(f32x4*)(outRow + jb) = z;
        return;
    }

    for (int jb = 0; jb < N_; jb += 16) {
        // on-the-fly u_j for token jb + c
        float2 pj = pos2[jb + c];
        fp16x2 px = pkb(pj.x), py = pkb(pj.y);

        // Layer1: h1 = relu(u_j + (b1 - u_i)) packed f16 — fragment-ready
        F16x8U A1[2];
        #pragma unroll
        for (int s = 0; s < 2; ++s)
            #pragma unroll
            for (int e2 = 0; e2 < 4; ++e2)
                A1[s].u[e2] = hmax0(px * w1a[s][e2] + (py * w1b[s][e2] + uin[s][e2]));

        // Layer2 transposed: lane (g,c) gets h2pre[pair c][hid 16n+4g+q]
        f32x4 acc[4];
        #pragma unroll
        for (int n = 0; n < 4; ++n) {
            acc[n] = __builtin_amdgcn_mfma_f32_16x16x32_f16(W2f[0][n].v, A1[0].v, b2v[n], 0, 0, 0);
            acc[n] = __builtin_amdgcn_mfma_f32_16x16x32_f16(W2f[1][n].v, A1[1].v, acc[n], 0, 0, 0);
        }

        // Layer3 A-frag register-only via permuted k-map
        F16x8U A3[2];
        #pragma unroll
        for (int s = 0; s < 2; ++s) {
            A3[s].u[0] = pkcvt_relu(acc[2*s][0],     acc[2*s][1]);
            A3[s].u[1] = pkcvt_relu(acc[2*s][2],     acc[2*s][3]);
            A3[s].u[2] = pkcvt_relu(acc[2*s + 1][0], acc[2*s + 1][1]);
            A3[s].u[3] = pkcvt_relu(acc[2*s + 1][2], acc[2*s + 1][3]);
        }

        f32x4 acc3 = { b3v, b3v, b3v, b3v };
        acc3 = __builtin_amdgcn_mfma_f32_16x16x32_f16(A3[0].v, W3g[0].v, acc3, 0, 0, 0);
        acc3 = __builtin_amdgcn_mfma_f32_16x16x32_f16(A3[1].v, W3g[1].v, acc3, 0, 0, 0);

        // j-mask + store (L2-cached; j-sequential per plane)
        const int4 mj = *(const int4*)&maskj[jb + 4*g];
        f32x4 o;
        o[0] = mj.x ? 0.f : acc3[0];
        o[1] = mj.y ? 0.f : acc3[1];
        o[2] = mj.z ? 0.f : acc3[2];
        o[3] = mj.w ? 0.f : acc3[3];
        *(f32x4*)(outRow + jb) = o;
    }
}

extern "C" void kernel_launch(void* const* d_in, const int* in_sizes, int n_in,
                              void* d_out, int out_size, void* d_ws, size_t ws_size,
                              hipStream_t stream) {
    const float* pos  = (const float*)d_in[0];
    const int*   mask = (const int*)d_in[1];
    const float* W1   = (const float*)d_in[2];
    const float* b1   = (const float*)d_in[3];
    const float* W2   = (const float*)d_in[4];
    const float* b2   = (const float*)d_in[5];
    const float* W3   = (const float*)d_in[6];
    const float* b3   = (const float*)d_in[7];
    float* out = (float*)d_out;

    dim3 grid(N_ / 4, B_);
    RelativePositionalBias_kernel<<<grid, dim3(256), 0, stream>>>(
        pos, mask, W1, b1, W2, b2, W3, b3, out);
}

// Round 10
// 62.581 us; speedup vs baseline: 1.3169x; 1.3169x over previous
//
#include <hip/hip_runtime.h>
#include <hip/hip_bf16.h>
#include <hip/hip_fp16.h>

#define B_   4
#define N_   1024
#define H_   16
#define HID_ 64
#define TI   16
#define TJ   128
#define USJ  36   // uint stride for uj/uin rows

typedef float    f32x4  __attribute__((ext_vector_type(4)));
typedef __fp16   fp16x2 __attribute__((ext_vector_type(2)));   // cvt_pkrtz result type
typedef _Float16 f16x8  __attribute__((ext_vector_type(8)));   // MFMA operand type
typedef unsigned int u32;

union F16x8U { u32 u[4]; f16x8 v; };

static __device__ __forceinline__ u32 pk(float a, float b) {
    union { fp16x2 f; u32 u; } r;
    r.f = __builtin_amdgcn_cvt_pkrtz(a, b);
    return r.u;
}
static __device__ __forceinline__ u32 pkadd_relu(u32 a, u32 b) {
    union { u32 u; fp16x2 f; } x, y, r;
    x.u = a; y.u = b;
    fp16x2 z = { (__fp16)0.f, (__fp16)0.f };
    fp16x2 s = x.f + y.f;
    r.f = __builtin_elementwise_max(s, z);
    return r.u;
}
static __device__ __forceinline__ u32 pkcvt_relu(float a, float b) {
    union { fp16x2 f; u32 u; } r;
    fp16x2 z = { (__fp16)0.f, (__fp16)0.f };
    fp16x2 s = __builtin_amdgcn_cvt_pkrtz(a, b);
    r.f = __builtin_elementwise_max(s, z);
    return r.u;
}

__global__ __launch_bounds__(256) void RelativePositionalBias_kernel(
    const float* __restrict__ pos,  // (B,N,2)
    const int*   __restrict__ mask, // (B,N) 0/1
    const float* __restrict__ W1,   // (2,64)
    const float* __restrict__ b1,   // (64)
    const float* __restrict__ W2,   // (64,64)
    const float* __restrict__ b2,   // (64)
    const float* __restrict__ W3,   // (64,16)
    const float* __restrict__ b3,   // (16)
    float* __restrict__ out)        // (B,16,N,N)
{
    __shared__ __align__(16) u32 ujL[TJ][USJ];    // u_j packed f16
    __shared__ __align__(16) u32 uinL[TI][USJ];   // (b1 - u_i) packed f16

    const int b  = blockIdx.z;
    const int i0 = blockIdx.y * TI;
    const int j0 = blockIdx.x * TJ;
    const int tid = threadIdx.x;
    const int w = tid >> 6;
    const int l = tid & 63;
    const int g = l >> 4;
    const int c = l & 15;

    // ---- Stage packed-f16 u for the 144 tokens (8 f16 per item) ----
    for (int it = tid; it < (TJ + TI) * 8; it += 256) {
        int r  = it >> 3;
        int qq = (it & 7) * 4;     // uint index base; covers k = 2*qq .. 2*qq+7
        int k0 = qq * 2;
        int tok = (r < TJ) ? (j0 + r) : (i0 + (r - TJ));
        float2 p  = *(const float2*)&pos[(b * N_ + tok) * 2];
        float4 a0 = *(const float4*)&W1[k0];
        float4 a1 = *(const float4*)&W1[k0 + 4];
        float4 c0 = *(const float4*)&W1[HID_ + k0];
        float4 c1 = *(const float4*)&W1[HID_ + k0 + 4];
        float u0 = p.x*a0.x + p.y*c0.x, u1 = p.x*a0.y + p.y*c0.y;
        float u2 = p.x*a0.z + p.y*c0.z, u3 = p.x*a0.w + p.y*c0.w;
        float u4 = p.x*a1.x + p.y*c1.x, u5 = p.x*a1.y + p.y*c1.y;
        float u6 = p.x*a1.z + p.y*c1.z, u7 = p.x*a1.w + p.y*c1.w;
        uint4 o;
        if (r < TJ) {
            o.x = pk(u0, u1); o.y = pk(u2, u3); o.z = pk(u4, u5); o.w = pk(u6, u7);
            *(uint4*)&ujL[r][qq] = o;
        } else {
            float4 ba = *(const float4*)&b1[k0];
            float4 bb = *(const float4*)&b1[k0 + 4];
            o.x = pk(ba.x - u0, ba.y - u1); o.y = pk(ba.z - u2, ba.w - u3);
            o.z = pk(bb.x - u4, bb.y - u5); o.w = pk(bb.z - u6, bb.w - u7);
            *(uint4*)&uinL[r - TJ][qq] = o;
        }
    }

    // ---- Weight fragments (f16). Identity k-map for L2, permuted for L3 ----
    F16x8U W2f[2][4];   // A-frag of mfma(W2^T, h1^T): W2[32s+8g+e][16n+c]
    #pragma unroll
    for (int s = 0; s < 2; ++s)
        #pragma unroll
        for (int n = 0; n < 4; ++n)
            #pragma unroll
            for (int e = 0; e < 8; ++e)
                W2f[s][n].v[e] = (_Float16)W2[(32*s + 8*g + e) * HID_ + 16*n + c];

    F16x8U W3g[2];      // B-frag, permuted k: hid = 32s + 16*(e>>2) + 4g + (e&3)
    #pragma unroll
    for (int s = 0; s < 2; ++s)
        #pragma unroll
        for (int e = 0; e < 8; ++e)
            W3g[s].v[e] = (_Float16)W3[(32*s + 16*(e>>2) + 4*g + (e&3)) * H_ + c];

    f32x4 b2v[4];
    #pragma unroll
    for (int n = 0; n < 4; ++n)
        b2v[n] = *(const f32x4*)&b2[16*n + 4*g];

    const float b3v = b3[c];
    const int* maskb = &mask[b * N_ + i0];
    // wave owns j = j0 + 32w + {0..31}: two 16-j groups (u=0,1)
    // j-masks for store mapping: lane (g,c) covers j = j0+32w+16u+4g+q, head c
    const int4 mj0 = *(const int4*)&mask[b * N_ + j0 + 32*w + 4*g];
    const int4 mj1 = *(const int4*)&mask[b * N_ + j0 + 32*w + 16 + 4*g];
    // plane base: head c, col j0+32w+4g
    float* const outBase = out + ((size_t)(b*H_ + c) << 20) + (size_t)(j0 + 32*w + 4*g)
                               + ((size_t)i0 << 10);

    __syncthreads();   // the ONLY barrier

    // Hoist the two packed j-rows for this lane: rows 32w+c and 32w+16+c
    const uint4 pj00 = *(const uint4*)&ujL[32*w + c][4*g];
    const uint4 pj01 = *(const uint4*)&ujL[32*w + c][16 + 4*g];
    const uint4 pj10 = *(const uint4*)&ujL[32*w + 16 + c][4*g];
    const uint4 pj11 = *(const uint4*)&ujL[32*w + 16 + c][16 + 4*g];

    #pragma unroll 2
    for (int t = 0; t < TI; ++t) {
        const int mi = maskb[t];
        float* const outRow = outBase + ((size_t)t << 10);
        f32x4 o0 = { 0.f, 0.f, 0.f, 0.f };
        f32x4 o1 = { 0.f, 0.f, 0.f, 0.f };

        if (!mi) {
            // ui shared by both j-groups (same i-row)
            const uint4 uiA = *(const uint4*)&uinL[t][4*g];
            const uint4 uiB = *(const uint4*)&uinL[t][16 + 4*g];

            #pragma unroll
            for (int u = 0; u < 2; ++u) {
                const uint4& pjA = u ? pj10 : pj00;
                const uint4& pjB = u ? pj11 : pj01;

                // Layer1: h1 = relu(u_j + (b1-u_i)) packed f16 — fragment-ready
                F16x8U A1[2];
                A1[0].u[0] = pkadd_relu(pjA.x, uiA.x);
                A1[0].u[1] = pkadd_relu(pjA.y, uiA.y);
                A1[0].u[2] = pkadd_relu(pjA.z, uiA.z);
                A1[0].u[3] = pkadd_relu(pjA.w, uiA.w);
                A1[1].u[0] = pkadd_relu(pjB.x, uiB.x);
                A1[1].u[1] = pkadd_relu(pjB.y, uiB.y);
                A1[1].u[2] = pkadd_relu(pjB.z, uiB.z);
                A1[1].u[3] = pkadd_relu(pjB.w, uiB.w);

                // Layer2 transposed: lane (g,c) gets h2pre[pair c][hid 16n+4g+q]
                f32x4 acc[4];
                #pragma unroll
                for (int n = 0; n < 4; ++n) {
                    acc[n] = __builtin_amdgcn_mfma_f32_16x16x32_f16(W2f[0][n].v, A1[0].v, b2v[n], 0, 0, 0);
                    acc[n] = __builtin_amdgcn_mfma_f32_16x16x32_f16(W2f[1][n].v, A1[1].v, acc[n], 0, 0, 0);
                }

                // Layer3 A-frag register-only via permuted k-map
                F16x8U A3[2];
                #pragma unroll
                for (int s = 0; s < 2; ++s) {
                    A3[s].u[0] = pkcvt_relu(acc[2*s][0],     acc[2*s][1]);
                    A3[s].u[1] = pkcvt_relu(acc[2*s][2],     acc[2*s][3]);
                    A3[s].u[2] = pkcvt_relu(acc[2*s + 1][0], acc[2*s + 1][1]);
                    A3[s].u[3] = pkcvt_relu(acc[2*s + 1][2], acc[2*s + 1][3]);
                }

                f32x4 acc3 = { b3v, b3v, b3v, b3v };
                acc3 = __builtin_amdgcn_mfma_f32_16x16x32_f16(A3[0].v, W3g[0].v, acc3, 0, 0, 0);
                acc3 = __builtin_amdgcn_mfma_f32_16x16x32_f16(A3[1].v, W3g[1].v, acc3, 0, 0, 0);

                const int4& mj = u ? mj1 : mj0;
                f32x4& o = u ? o1 : o0;
                o[0] = mj.x ? 0.f : acc3[0];
                o[1] = mj.y ? 0.f : acc3[1];
                o[2] = mj.z ? 0.f : acc3[2];
                o[3] = mj.w ? 0.f : acc3[3];
            }
        }

        // two stores 64B apart per plane -> L2 combines into full 128B lines
        *(f32x4*)(outRow)      = o0;
        *(f32x4*)(outRow + 16) = o1;
    }
}

extern "C" void kernel_launch(void* const* d_in, const int* in_sizes, int n_in,
                              void* d_out, int out_size, void* d_ws, size_t ws_size,
                              hipStream_t stream) {
    const float* pos  = (const float*)d_in[0];
    const int*   mask = (const int*)d_in[1];
    const float* W1   = (const float*)d_in[2];
    const float* b1   = (const float*)d_in[3];
    const float* W2   = (const float*)d_in[4];
    const float* b2   = (const float*)d_in[5];
    const float* W3   = (const float*)d_in[6];
    const float* b3   = (const float*)d_in[7];
    float* out = (float*)d_out;

    dim3 grid(N_ / TJ, N_ / TI, B_);
    RelativePositionalBias_kernel<<<grid, dim3(256), 0, stream>>>(
        pos, mask, W1, b1, W2, b2, W3, b3, out);
}

// Round 11
// 58.877 us; speedup vs baseline: 1.3997x; 1.0629x over previous
//
#include <hip/hip_runtime.h>
#include <hip/hip_bf16.h>
#include <hip/hip_fp16.h>

#define B_   4
#define N_   1024
#define H_   16
#define HID_ 64
#define TI   16

typedef float    f32x4  __attribute__((ext_vector_type(4)));
typedef __fp16   fp16x2 __attribute__((ext_vector_type(2)));   // cvt_pkrtz result type
typedef _Float16 f16x8  __attribute__((ext_vector_type(8)));   // MFMA operand type
typedef unsigned int u32;

union F16x8U { u32 u[4]; f16x8 v; };

static __device__ __forceinline__ u32 pk(float a, float b) {
    union { fp16x2 f; u32 u; } r;
    r.f = __builtin_amdgcn_cvt_pkrtz(a, b);
    return r.u;
}
static __device__ __forceinline__ u32 pkadd_relu(u32 a, u32 b) {
    union { u32 u; fp16x2 f; } x, y, r;
    x.u = a; y.u = b;
    fp16x2 z = { (__fp16)0.f, (__fp16)0.f };
    fp16x2 s = x.f + y.f;
    r.f = __builtin_elementwise_max(s, z);
    return r.u;
}
static __device__ __forceinline__ u32 pkcvt_relu(float a, float b) {
    union { fp16x2 f; u32 u; } r;
    fp16x2 z = { (__fp16)0.f, (__fp16)0.f };
    fp16x2 s = __builtin_amdgcn_cvt_pkrtz(a, b);
    r.f = __builtin_elementwise_max(s, z);
    return r.u;
}

__global__ __launch_bounds__(512, 2) void RelativePositionalBias_kernel(
    const float* __restrict__ pos,  // (B,N,2)
    const int*   __restrict__ mask, // (B,N) 0/1
    const float* __restrict__ W1,   // (2,64)
    const float* __restrict__ b1,   // (64)
    const float* __restrict__ W2,   // (64,64)
    const float* __restrict__ b2,   // (64)
    const float* __restrict__ W3,   // (64,16)
    const float* __restrict__ b3,   // (16)
    float* __restrict__ out)        // (B,16,N,N)
{
    // Full j-row staged: 1024 tokens x 64 f16 = 128KB; XOR-swizzled, no padding.
    __shared__ __align__(16) u32 ujL[N_][32];
    __shared__ __align__(16) u32 uinL[TI][32];

    const int b   = blockIdx.y;
    const int i0  = blockIdx.x * TI;
    const int tid = threadIdx.x;
    const int w = tid >> 6;      // wave 0..7, owns j-chunk [128w, 128w+128)
    const int l = tid & 63;
    const int g = l >> 4;        // quarter-wave group 0..3
    const int c = l & 15;        // lane-within-group 0..15

    // ---- Stage packed-f16 u for 1024 j-tokens + 16 i-tokens ----
    for (int it = tid; it < (N_ + TI) * 8; it += 512) {
        int r  = it >> 3;          // token slot 0..1039
        int qq = it & 7;           // 4-uint group: covers k = 8qq..8qq+7
        int k0 = qq * 8;
        int tok = (r < N_) ? r : (i0 + (r - N_));
        float2 p  = *(const float2*)&pos[(b * N_ + tok) * 2];
        float4 a0 = *(const float4*)&W1[k0];
        float4 a1 = *(const float4*)&W1[k0 + 4];
        float4 c0 = *(const float4*)&W1[HID_ + k0];
        float4 c1 = *(const float4*)&W1[HID_ + k0 + 4];
        float u0 = p.x*a0.x + p.y*c0.x, u1 = p.x*a0.y + p.y*c0.y;
        float u2 = p.x*a0.z + p.y*c0.z, u3 = p.x*a0.w + p.y*c0.w;
        float u4 = p.x*a1.x + p.y*c1.x, u5 = p.x*a1.y + p.y*c1.y;
        float u6 = p.x*a1.z + p.y*c1.z, u7 = p.x*a1.w + p.y*c1.w;
        const int col = ((qq ^ (r & 7)) << 2);   // XOR swizzle, 16B-aligned
        uint4 o;
        if (r < N_) {
            o.x = pk(u0, u1); o.y = pk(u2, u3); o.z = pk(u4, u5); o.w = pk(u6, u7);
            *(uint4*)&ujL[r][col] = o;
        } else {
            float4 ba = *(const float4*)&b1[k0];
            float4 bb = *(const float4*)&b1[k0 + 4];
            o.x = pk(ba.x - u0, ba.y - u1); o.y = pk(ba.z - u2, ba.w - u3);
            o.z = pk(bb.x - u4, bb.y - u5); o.w = pk(bb.z - u6, bb.w - u7);
            *(uint4*)&uinL[r - N_][col] = o;
        }
    }

    // ---- Weight fragments (f16). Identity k-map for L2, permuted for L3 ----
    F16x8U W2f[2][4];   // A-frag of mfma(W2^T, h1^T): W2[32s+8g+e][16n+c]
    #pragma unroll
    for (int s = 0; s < 2; ++s)
        #pragma unroll
        for (int n = 0; n < 4; ++n)
            #pragma unroll
            for (int e = 0; e < 8; ++e)
                W2f[s][n].v[e] = (_Float16)W2[(32*s + 8*g + e) * HID_ + 16*n + c];

    F16x8U W3g[2];      // B-frag, permuted k: hid = 32s + 16*(e>>2) + 4g + (e&3)
    #pragma unroll
    for (int s = 0; s < 2; ++s)
        #pragma unroll
        for (int e = 0; e < 8; ++e)
            W3g[s].v[e] = (_Float16)W3[(32*s + 16*(e>>2) + 4*g + (e&3)) * H_ + c];

    f32x4 b2v[4];
    #pragma unroll
    for (int n = 0; n < 4; ++n)
        b2v[n] = *(const f32x4*)&b2[16*n + 4*g];
    const float b3v = b3[c];

    // ---- i-mask bitmask (no global loads in main loop) ----
    const int* maskb = &mask[b * N_ + i0];
    u32 mrow = 0;
    #pragma unroll
    for (int tt = 0; tt < 4; ++tt) {
        int4 m = *(const int4*)&maskb[tt * 4];
        mrow |= (m.x ? 1u : 0u) << (4*tt);
        mrow |= (m.y ? 1u : 0u) << (4*tt + 1);
        mrow |= (m.z ? 1u : 0u) << (4*tt + 2);
        mrow |= (m.w ? 1u : 0u) << (4*tt + 3);
    }

    // ---- j-mask multipliers: lane (g,c), jj: j = 128w + 16jj + 4g + q ----
    f32x4 mmul[8];
    #pragma unroll
    for (int jj = 0; jj < 8; ++jj) {
        int4 mj = *(const int4*)&mask[b * N_ + 128*w + 16*jj + 4*g];
        mmul[jj][0] = mj.x ? 0.f : 1.f;
        mmul[jj][1] = mj.y ? 0.f : 1.f;
        mmul[jj][2] = mj.z ? 0.f : 1.f;
        mmul[jj][3] = mj.w ? 0.f : 1.f;
    }

    // plane base: head c, row i0, col 128w+4g
    float* const planeBase = out + ((size_t)(b*H_ + c) << 20) + ((size_t)i0 << 10)
                                 + (size_t)(128*w + 4*g);

    __syncthreads();   // the ONLY barrier

    const f32x4 zero4 = { 0.f, 0.f, 0.f, 0.f };

    for (int t = 0; t < TI; ++t) {
        float* const rowp = planeBase + ((size_t)t << 10);

        if ((mrow >> t) & 1) {     // whole i-row masked: stream zeros
            #pragma unroll
            for (int jj = 0; jj < 8; ++jj)
                *(f32x4*)(rowp + 16*jj) = zero4;
            continue;
        }

        const int tb = t & 7;
        const uint4 uiA = *(const uint4*)&uinL[t][(g ^ tb) << 2];
        const uint4 uiB = *(const uint4*)&uinL[t][((4 + g) ^ tb) << 2];

        #pragma unroll
        for (int jj = 0; jj < 8; ++jj) {
            const int jrow = 128*w + 16*jj + c;
            const int jb = c & 7;                    // jrow & 7
            const uint4 pjA = *(const uint4*)&ujL[jrow][(g ^ jb) << 2];
            const uint4 pjB = *(const uint4*)&ujL[jrow][((4 + g) ^ jb) << 2];

            // Layer1: h1 = relu(u_j + (b1-u_i)) packed f16 — fragment-ready
            F16x8U A1[2];
            A1[0].u[0] = pkadd_relu(pjA.x, uiA.x);
            A1[0].u[1] = pkadd_relu(pjA.y, uiA.y);
            A1[0].u[2] = pkadd_relu(pjA.z, uiA.z);
            A1[0].u[3] = pkadd_relu(pjA.w, uiA.w);
            A1[1].u[0] = pkadd_relu(pjB.x, uiB.x);
            A1[1].u[1] = pkadd_relu(pjB.y, uiB.y);
            A1[1].u[2] = pkadd_relu(pjB.z, uiB.z);
            A1[1].u[3] = pkadd_relu(pjB.w, uiB.w);

            // Layer2 transposed: lane (g,c) gets h2pre[pair c][hid 16n+4g+q]
            f32x4 acc[4];
            #pragma unroll
            for (int n = 0; n < 4; ++n) {
                acc[n] = __builtin_amdgcn_mfma_f32_16x16x32_f16(W2f[0][n].v, A1[0].v, b2v[n], 0, 0, 0);
                acc[n] = __builtin_amdgcn_mfma_f32_16x16x32_f16(W2f[1][n].v, A1[1].v, acc[n], 0, 0, 0);
            }

            // Layer3 A-frag register-only via permuted k-map
            F16x8U A3[2];
            #pragma unroll
            for (int s = 0; s < 2; ++s) {
                A3[s].u[0] = pkcvt_relu(acc[2*s][0],     acc[2*s][1]);
                A3[s].u[1] = pkcvt_relu(acc[2*s][2],     acc[2*s][3]);
                A3[s].u[2] = pkcvt_relu(acc[2*s + 1][0], acc[2*s + 1][1]);
                A3[s].u[3] = pkcvt_relu(acc[2*s + 1][2], acc[2*s + 1][3]);
            }

            f32x4 acc3 = { b3v, b3v, b3v, b3v };
            acc3 = __builtin_amdgcn_mfma_f32_16x16x32_f16(A3[0].v, W3g[0].v, acc3, 0, 0, 0);
            acc3 = __builtin_amdgcn_mfma_f32_16x16x32_f16(A3[1].v, W3g[1].v, acc3, 0, 0, 0);

            // j-mask via 0/1 multiplier (values finite; exact 0 where masked)
            *(f32x4*)(rowp + 16*jj) = acc3 * mmul[jj];
        }
    }
}

extern "C" void kernel_launch(void* const* d_in, const int* in_sizes, int n_in,
                              void* d_out, int out_size, void* d_ws, size_t ws_size,
                              hipStream_t stream) {
    const float* pos  = (const float*)d_in[0];
    const int*   mask = (const int*)d_in[1];
    const float* W1   = (const float*)d_in[2];
    const float* b1   = (const float*)d_in[3];
    const float* W2   = (const float*)d_in[4];
    const float* b2   = (const float*)d_in[5];
    const float* W3   = (const float*)d_in[6];
    const float* b3   = (const float*)d_in[7];
    float* out = (float*)d_out;

    dim3 grid(N_ / TI, B_);   // 64 x 4 = 256 blocks = 1 per CU
    RelativePositionalBias_kernel<<<grid, dim3(512), 0, stream>>>(
        pos, mask, W1, b1, W2, b2, W3, b3, out);
}

// Round 12
// 57.282 us; speedup vs baseline: 1.4387x; 1.0279x over previous
//
#include <hip/hip_runtime.h>
#include <hip/hip_bf16.h>
#include <hip/hip_fp16.h>

#define B_   4
#define N_   1024
#define H_   16
#define HID_ 64
#define TI   16
#define JH   512   // j-chunk per block

typedef float    f32x4  __attribute__((ext_vector_type(4)));
typedef __fp16   fp16x2 __attribute__((ext_vector_type(2)));   // cvt_pkrtz result type
typedef _Float16 f16x8  __attribute__((ext_vector_type(8)));   // MFMA operand type
typedef unsigned int u32;

union F16x8U { u32 u[4]; f16x8 v; };

static __device__ __forceinline__ u32 pk(float a, float b) {
    union { fp16x2 f; u32 u; } r;
    r.f = __builtin_amdgcn_cvt_pkrtz(a, b);
    return r.u;
}
static __device__ __forceinline__ u32 pkadd_relu(u32 a, u32 b) {
    union { u32 u; fp16x2 f; } x, y, r;
    x.u = a; y.u = b;
    fp16x2 z = { (__fp16)0.f, (__fp16)0.f };
    fp16x2 s = x.f + y.f;
    r.f = __builtin_elementwise_max(s, z);
    return r.u;
}
static __device__ __forceinline__ u32 pkcvt_relu(float a, float b) {
    union { fp16x2 f; u32 u; } r;
    fp16x2 z = { (__fp16)0.f, (__fp16)0.f };
    fp16x2 s = __builtin_amdgcn_cvt_pkrtz(a, b);
    r.f = __builtin_elementwise_max(s, z);
    return r.u;
}

__global__ __launch_bounds__(512, 2) void RelativePositionalBias_kernel(
    const float* __restrict__ pos,  // (B,N,2)
    const int*   __restrict__ mask, // (B,N) 0/1
    const float* __restrict__ W1,   // (2,64)
    const float* __restrict__ b1,   // (64)
    const float* __restrict__ W2,   // (64,64)
    const float* __restrict__ b2,   // (64)
    const float* __restrict__ W3,   // (64,16)
    const float* __restrict__ b3,   // (16)
    float* __restrict__ out)        // (B,16,N,N)
{
    // Half j-row staged: 512 tokens x 128B = 64KB; XOR-swizzled, no padding.
    __shared__ __align__(16) u32 ujL[JH][32];
    __shared__ __align__(16) u32 uinL[TI][32];

    const int b   = blockIdx.z;
    const int i0  = blockIdx.y * TI;
    const int j0  = blockIdx.x * JH;
    const int tid = threadIdx.x;
    const int w = tid >> 6;      // wave 0..7, owns j-subrange [j0+64w, j0+64w+64)
    const int l = tid & 63;
    const int g = l >> 4;        // quarter-wave group 0..3
    const int c = l & 15;        // lane-within-group 0..15

    // ---- Stage packed-f16 u for 512 j-tokens + 16 i-tokens ----
    for (int it = tid; it < (JH + TI) * 8; it += 512) {
        int r  = it >> 3;          // token slot 0..527
        int qq = it & 7;           // 4-uint group: covers k = 8qq..8qq+7
        int k0 = qq * 8;
        int tok = (r < JH) ? (j0 + r) : (i0 + (r - JH));
        float2 p  = *(const float2*)&pos[(b * N_ + tok) * 2];
        float4 a0 = *(const float4*)&W1[k0];
        float4 a1 = *(const float4*)&W1[k0 + 4];
        float4 c0 = *(const float4*)&W1[HID_ + k0];
        float4 c1 = *(const float4*)&W1[HID_ + k0 + 4];
        float u0 = p.x*a0.x + p.y*c0.x, u1 = p.x*a0.y + p.y*c0.y;
        float u2 = p.x*a0.z + p.y*c0.z, u3 = p.x*a0.w + p.y*c0.w;
        float u4 = p.x*a1.x + p.y*c1.x, u5 = p.x*a1.y + p.y*c1.y;
        float u6 = p.x*a1.z + p.y*c1.z, u7 = p.x*a1.w + p.y*c1.w;
        const int col = ((qq ^ (r & 7)) << 2);   // XOR swizzle, 16B-aligned
        uint4 o;
        if (r < JH) {
            o.x = pk(u0, u1); o.y = pk(u2, u3); o.z = pk(u4, u5); o.w = pk(u6, u7);
            *(uint4*)&ujL[r][col] = o;
        } else {
            float4 ba = *(const float4*)&b1[k0];
            float4 bb = *(const float4*)&b1[k0 + 4];
            o.x = pk(ba.x - u0, ba.y - u1); o.y = pk(ba.z - u2, ba.w - u3);
            o.z = pk(bb.x - u4, bb.y - u5); o.w = pk(bb.z - u6, bb.w - u7);
            *(uint4*)&uinL[r - JH][col] = o;
        }
    }

    // ---- Weight fragments (f16). Identity k-map for L2, permuted for L3 ----
    F16x8U W2f[2][4];   // A-frag of mfma(W2^T, h1^T): W2[32s+8g+e][16n+c]
    #pragma unroll
    for (int s = 0; s < 2; ++s)
        #pragma unroll
        for (int n = 0; n < 4; ++n)
            #pragma unroll
            for (int e = 0; e < 8; ++e)
                W2f[s][n].v[e] = (_Float16)W2[(32*s + 8*g + e) * HID_ + 16*n + c];

    F16x8U W3g[2];      // B-frag, permuted k: hid = 32s + 16*(e>>2) + 4g + (e&3)
    #pragma unroll
    for (int s = 0; s < 2; ++s)
        #pragma unroll
        for (int e = 0; e < 8; ++e)
            W3g[s].v[e] = (_Float16)W3[(32*s + 16*(e>>2) + 4*g + (e&3)) * H_ + c];

    f32x4 b2v[4];
    #pragma unroll
    for (int n = 0; n < 4; ++n)
        b2v[n] = *(const f32x4*)&b2[16*n + 4*g];
    const float b3v = b3[c];

    // ---- i-mask bitmask (no global loads in main loop) ----
    const int* maskb = &mask[b * N_ + i0];
    u32 mrow = 0;
    #pragma unroll
    for (int tt = 0; tt < 4; ++tt) {
        int4 m = *(const int4*)&maskb[tt * 4];
        mrow |= (m.x ? 1u : 0u) << (4*tt);
        mrow |= (m.y ? 1u : 0u) << (4*tt + 1);
        mrow |= (m.z ? 1u : 0u) << (4*tt + 2);
        mrow |= (m.w ? 1u : 0u) << (4*tt + 3);
    }

    // ---- j-mask multipliers: lane (g,c), jj: j = j0 + 64w + 16jj + 4g + q ----
    f32x4 mmul[4];
    #pragma unroll
    for (int jj = 0; jj < 4; ++jj) {
        int4 mj = *(const int4*)&mask[b * N_ + j0 + 64*w + 16*jj + 4*g];
        mmul[jj][0] = mj.x ? 0.f : 1.f;
        mmul[jj][1] = mj.y ? 0.f : 1.f;
        mmul[jj][2] = mj.z ? 0.f : 1.f;
        mmul[jj][3] = mj.w ? 0.f : 1.f;
    }

    // plane base: head c, row i0, col j0+64w+4g
    float* const planeBase = out + ((size_t)(b*H_ + c) << 20) + ((size_t)i0 << 10)
                                 + (size_t)(j0 + 64*w + 4*g);

    __syncthreads();   // the ONLY barrier

    const f32x4 zero4 = { 0.f, 0.f, 0.f, 0.f };

    for (int t = 0; t < TI; ++t) {
        float* const rowp = planeBase + ((size_t)t << 10);

        if ((mrow >> t) & 1) {     // whole i-row masked: stream zeros
            #pragma unroll
            for (int jj = 0; jj < 4; ++jj)
                *(f32x4*)(rowp + 16*jj) = zero4;
            continue;
        }

        const int tb = t & 7;
        const uint4 uiA = *(const uint4*)&uinL[t][(g ^ tb) << 2];
        const uint4 uiB = *(const uint4*)&uinL[t][((4 + g) ^ tb) << 2];

        #pragma unroll
        for (int jj = 0; jj < 4; ++jj) {
            const int jrow = 64*w + 16*jj + c;       // local ujL row
            const int jb = c & 7;                    // jrow & 7 (16jj,64w ≡ 0 mod 8)
            const uint4 pjA = *(const uint4*)&ujL[jrow][(g ^ jb) << 2];
            const uint4 pjB = *(const uint4*)&ujL[jrow][((4 + g) ^ jb) << 2];

            // Layer1: h1 = relu(u_j + (b1-u_i)) packed f16 — fragment-ready
            F16x8U A1[2];
            A1[0].u[0] = pkadd_relu(pjA.x, uiA.x);
            A1[0].u[1] = pkadd_relu(pjA.y, uiA.y);
            A1[0].u[2] = pkadd_relu(pjA.z, uiA.z);
            A1[0].u[3] = pkadd_relu(pjA.w, uiA.w);
            A1[1].u[0] = pkadd_relu(pjB.x, uiB.x);
            A1[1].u[1] = pkadd_relu(pjB.y, uiB.y);
            A1[1].u[2] = pkadd_relu(pjB.z, uiB.z);
            A1[1].u[3] = pkadd_relu(pjB.w, uiB.w);

            // Layer2 transposed: lane (g,c) gets h2pre[pair c][hid 16n+4g+q]
            f32x4 acc[4];
            #pragma unroll
            for (int n = 0; n < 4; ++n) {
                acc[n] = __builtin_amdgcn_mfma_f32_16x16x32_f16(W2f[0][n].v, A1[0].v, b2v[n], 0, 0, 0);
                acc[n] = __builtin_amdgcn_mfma_f32_16x16x32_f16(W2f[1][n].v, A1[1].v, acc[n], 0, 0, 0);
            }

            // Layer3 A-frag register-only via permuted k-map
            F16x8U A3[2];
            #pragma unroll
            for (int s = 0; s < 2; ++s) {
                A3[s].u[0] = pkcvt_relu(acc[2*s][0],     acc[2*s][1]);
                A3[s].u[1] = pkcvt_relu(acc[2*s][2],     acc[2*s][3]);
                A3[s].u[2] = pkcvt_relu(acc[2*s + 1][0], acc[2*s + 1][1]);
                A3[s].u[3] = pkcvt_relu(acc[2*s + 1][2], acc[2*s + 1][3]);
            }

            f32x4 acc3 = { b3v, b3v, b3v, b3v };
            acc3 = __builtin_amdgcn_mfma_f32_16x16x32_f16(A3[0].v, W3g[0].v, acc3, 0, 0, 0);
            acc3 = __builtin_amdgcn_mfma_f32_16x16x32_f16(A3[1].v, W3g[1].v, acc3, 0, 0, 0);

            // j-mask via 0/1 multiplier (values finite; exact 0 where masked)
            *(f32x4*)(rowp + 16*jj) = acc3 * mmul[jj];
        }
    }
}

extern "C" void kernel_launch(void* const* d_in, const int* in_sizes, int n_in,
                              void* d_out, int out_size, void* d_ws, size_t ws_size,
                              hipStream_t stream) {
    const float* pos  = (const float*)d_in[0];
    const int*   mask = (const int*)d_in[1];
    const float* W1   = (const float*)d_in[2];
    const float* b1   = (const float*)d_in[3];
    const float* W2   = (const float*)d_in[4];
    const float* b2   = (const float*)d_in[5];
    const float* W3   = (const float*)d_in[6];
    const float* b3   = (const float*)d_in[7];
    float* out = (float*)d_out;

    dim3 grid(N_ / JH, N_ / TI, B_);   // 2 x 64 x 4 = 512 blocks -> 2 per CU
    RelativePositionalBias_kernel<<<grid, dim3(512), 0, stream>>>(
        pos, mask, W1, b1, W2, b2, W3, b3, out);
}